// Round 15
// baseline (2003.194 us; speedup 1.0000x reference)
//
#include <hip/hip_runtime.h>

#define Bsz 64
#define Lsz 4096
#define Dsz 512
#define Hsz 512
#define Usz 256
#define LT  64
#define NLB (Lsz / LT)          // 64 L-tiles per batch -> 4096 blocks

typedef __attribute__((ext_vector_type(8))) short s8v;     // bf16x8 MFMA frag
typedef __attribute__((ext_vector_type(4))) float f4v;
typedef __attribute__((ext_vector_type(8))) unsigned short u16x8;

// XOR swizzle on a [64][512]-short row: 16B slot ^= row&7 (bijective, b128-aligned)
#define SW(r, c) (((((c) >> 3) ^ ((r) & 7)) << 3) | ((c) & 7))

__device__ __forceinline__ unsigned short f2bf(float f) {
    unsigned int u = __float_as_uint(f);
    u += 0x7FFFu + ((u >> 16) & 1u);   // RNE
    return (unsigned short)(u >> 16);
}
__device__ __forceinline__ float bf2f(unsigned int lo16) {
    return __uint_as_float(lo16 << 16);
}
__device__ __forceinline__ void barrier_lds() {
    asm volatile("s_waitcnt lgkmcnt(0)" ::: "memory");
    __builtin_amdgcn_s_barrier();
}

// ws layout
//   [0,     256K)      : W1T bf16 [256][512]
//   [256K,  512K)      : hp_part f32 [4][64][256]
//   [512K, 1536K)      : el_arr f32 [64][4096]
//   [1536K, +256B)     : den f32 [64]
//   [1536K+256, +128K) : ctx_acc f32 [64][512]
//   [2M, 2M+64K)       : ablation dump (scratch, not part of outputs)

__global__ __launch_bounds__(256) void k_prep(const float* __restrict__ W1,
                                              const float* __restrict__ hidden,
                                              const float* __restrict__ W2,
                                              unsigned short* __restrict__ W1T,
                                              float* __restrict__ hp_part,
                                              float* __restrict__ den,
                                              float* __restrict__ ctx_acc) {
    int blk = blockIdx.x, tid = threadIdx.x;
    if (blk < 32) {
        __shared__ unsigned short Lt[64][72];
        int kb = blk >> 2, ub = blk & 3;
        {
            int rr = tid >> 2, c16 = (tid & 3) * 16;
            const float* src = W1 + (size_t)(kb * 64 + rr) * Usz + ub * 64 + c16;
            f4v v0 = *reinterpret_cast<const f4v*>(src);
            f4v v1 = *reinterpret_cast<const f4v*>(src + 4);
            f4v v2 = *reinterpret_cast<const f4v*>(src + 8);
            f4v v3 = *reinterpret_cast<const f4v*>(src + 12);
            u16x8 o0 = { f2bf(v0.x), f2bf(v0.y), f2bf(v0.z), f2bf(v0.w),
                         f2bf(v1.x), f2bf(v1.y), f2bf(v1.z), f2bf(v1.w) };
            u16x8 o1 = { f2bf(v2.x), f2bf(v2.y), f2bf(v2.z), f2bf(v2.w),
                         f2bf(v3.x), f2bf(v3.y), f2bf(v3.z), f2bf(v3.w) };
            *reinterpret_cast<u16x8*>(&Lt[rr][c16])     = o0;
            *reinterpret_cast<u16x8*>(&Lt[rr][c16 + 8]) = o1;
        }
        __syncthreads();
        {
            int ur = tid >> 2, k16 = (tid & 3) * 16;
            u16x8 o0, o1;
#pragma unroll
            for (int i = 0; i < 8; ++i) o0[i] = Lt[k16 + i][ur];
#pragma unroll
            for (int i = 0; i < 8; ++i) o1[i] = Lt[k16 + 8 + i][ur];
            unsigned short* dst = W1T + (size_t)(ub * 64 + ur) * Dsz + kb * 64 + k16;
            *reinterpret_cast<u16x8*>(dst)     = o0;
            *reinterpret_cast<u16x8*>(dst + 8) = o1;
        }
    } else if (blk < 288) {
        int idx = blk - 32;
        int kq = idx >> 6, b = idx & 63;
        const float* hrow = hidden + (size_t)b * Hsz + kq * 128;
        const float* w2p  = W2 + (size_t)(kq * 128) * Usz + tid;
        float a0 = 0.f, a1 = 0.f, a2 = 0.f, a3 = 0.f;
#pragma unroll 8
        for (int k = 0; k < 128; k += 4) {
            a0 = fmaf(hrow[k + 0], w2p[(size_t)(k + 0) * Usz], a0);
            a1 = fmaf(hrow[k + 1], w2p[(size_t)(k + 1) * Usz], a1);
            a2 = fmaf(hrow[k + 2], w2p[(size_t)(k + 2) * Usz], a2);
            a3 = fmaf(hrow[k + 3], w2p[(size_t)(k + 3) * Usz], a3);
        }
        hp_part[((size_t)kq * Bsz + b) * Usz + tid] = (a0 + a1) + (a2 + a3);
    } else {
        int b = blk - 288;
        if (tid == 0) den[b] = 0.f;
        ctx_acc[b * Dsz + tid] = 0.f;
        ctx_acc[b * Dsz + 256 + tid] = 0.f;
    }
}

// ===================== REAL main kernel (R11, best known) =====================
__global__ void __launch_bounds__(512)
__attribute__((amdgpu_waves_per_eu(4, 4))) k_score_ctx(
    const float* __restrict__ feat, const unsigned short* __restrict__ W1T,
    const float* __restrict__ hp_part, const float* __restrict__ W1b,
    const float* __restrict__ W2b, const float* __restrict__ Vk,
    const float* __restrict__ Vb, float* __restrict__ el_arr,
    float* __restrict__ den, float* __restrict__ ctx_acc)
{
    __shared__ __align__(16) unsigned short A[LT][Dsz];  // 64 KiB, swizzled
    __shared__ float hp[Usz], vv[Usz];
    __shared__ float spart[8][LT];
    __shared__ float el[LT];
    __shared__ float pc[2][Dsz];

    const int tid  = threadIdx.x;
    const int w    = tid >> 6;
    const int lane = tid & 63;
    const int lr   = lane & 15;
    const int lg   = lane >> 4;
    const int b    = blockIdx.x >> 6;
    const int lb   = blockIdx.x & 63;
    const int l0   = lb * LT;

    const int srow = tid >> 3;
    const int sfc  = (tid & 7) * 16;
    const float* fb = feat + ((size_t)b * Lsz + l0 + srow) * Dsz + sfc;

    f4v st[2][4];
#pragma unroll
    for (int i = 0; i < 4; ++i) st[0][i] = *reinterpret_cast<const f4v*>(fb + i * 4);
#pragma unroll
    for (int i = 0; i < 4; ++i) st[1][i] = *reinterpret_cast<const f4v*>(fb + 128 + i * 4);
    __builtin_amdgcn_sched_barrier(0);

    if (tid < Usz) {
        const float* hpb = hp_part + (size_t)b * Usz + tid;
        hp[tid] = (hpb[0] + hpb[Bsz * Usz]) + (hpb[2 * Bsz * Usz] + hpb[3 * Bsz * Usz])
                + W1b[tid] + W2b[tid];
        vv[tid] = Vk[tid];
    }
    {
        u16x8 o0 = { f2bf(st[0][0].x), f2bf(st[0][0].y), f2bf(st[0][0].z), f2bf(st[0][0].w),
                     f2bf(st[0][1].x), f2bf(st[0][1].y), f2bf(st[0][1].z), f2bf(st[0][1].w) };
        u16x8 o1 = { f2bf(st[0][2].x), f2bf(st[0][2].y), f2bf(st[0][2].z), f2bf(st[0][2].w),
                     f2bf(st[0][3].x), f2bf(st[0][3].y), f2bf(st[0][3].z), f2bf(st[0][3].w) };
        *reinterpret_cast<u16x8*>(&A[srow][SW(srow, sfc)])     = o0;
        *reinterpret_cast<u16x8*>(&A[srow][SW(srow, sfc + 8)]) = o1;
    }
    barrier_lds();

    const unsigned short* bp0 = W1T + (size_t)(w * 32 + lr) * Dsz + lg * 8;
    const unsigned short* bp1 = bp0 + 16 * Dsz;
    f4v acc[4][2];
#pragma unroll
    for (int mf = 0; mf < 4; ++mf) {
        acc[mf][0] = (f4v){0.f, 0.f, 0.f, 0.f};
        acc[mf][1] = (f4v){0.f, 0.f, 0.f, 0.f};
    }

#pragma unroll
    for (int c = 0; c < 4; ++c) {
        s8v bq[4][2];
#pragma unroll
        for (int k = 0; k < 4; ++k) {
            bq[k][0] = *reinterpret_cast<const s8v*>(bp0 + (c * 4 + k) * 32);
            bq[k][1] = *reinterpret_cast<const s8v*>(bp1 + (c * 4 + k) * 32);
        }
        __builtin_amdgcn_sched_barrier(0);
        if (c < 2) {
#pragma unroll
            for (int i = 0; i < 4; ++i)
                st[c & 1][i] = *reinterpret_cast<const f4v*>(fb + (c + 2) * 128 + i * 4);
        }
        __builtin_amdgcn_sched_barrier(0);
#pragma unroll
        for (int k = 0; k < 4; ++k) {
            const int kof = (c * 4 + k) * 32 + lg * 8;
#pragma unroll
            for (int mf = 0; mf < 4; ++mf) {
                const int row = mf * 16 + lr;
                s8v a = *reinterpret_cast<const s8v*>(&A[row][SW(row, kof)]);
                acc[mf][0] = __builtin_amdgcn_mfma_f32_16x16x32_bf16(a, bq[k][0], acc[mf][0], 0, 0, 0);
                acc[mf][1] = __builtin_amdgcn_mfma_f32_16x16x32_bf16(a, bq[k][1], acc[mf][1], 0, 0, 0);
            }
        }
        __builtin_amdgcn_sched_barrier(0);
        if (c < 3) {
            const int cc = (c + 1) * 128 + sfc;
            const f4v* s = st[(c + 1) & 1];
            u16x8 o0 = { f2bf(s[0].x), f2bf(s[0].y), f2bf(s[0].z), f2bf(s[0].w),
                         f2bf(s[1].x), f2bf(s[1].y), f2bf(s[1].z), f2bf(s[1].w) };
            u16x8 o1 = { f2bf(s[2].x), f2bf(s[2].y), f2bf(s[2].z), f2bf(s[2].w),
                         f2bf(s[3].x), f2bf(s[3].y), f2bf(s[3].z), f2bf(s[3].w) };
            *reinterpret_cast<u16x8*>(&A[srow][SW(srow, cc)])     = o0;
            *reinterpret_cast<u16x8*>(&A[srow][SW(srow, cc + 8)]) = o1;
            barrier_lds();
        }
    }

    {
        float rs[4][4];
#pragma unroll
        for (int mf = 0; mf < 4; ++mf)
#pragma unroll
            for (int r = 0; r < 4; ++r) rs[mf][r] = 0.f;
#pragma unroll
        for (int mf = 0; mf < 4; ++mf)
#pragma unroll
            for (int nf = 0; nf < 2; ++nf) {
                int col = w * 32 + nf * 16 + lr;
                float hpv = hp[col], vvv = vv[col];
#pragma unroll
                for (int r = 0; r < 4; ++r) {
                    float x = acc[mf][nf][r] + hpv;
                    float e = __expf(2.f * x);
                    rs[mf][r] = fmaf(1.f - 2.f / (e + 1.f), vvv, rs[mf][r]);
                }
            }
#pragma unroll
        for (int off = 1; off < 16; off <<= 1)
#pragma unroll
            for (int mf = 0; mf < 4; ++mf)
#pragma unroll
                for (int r = 0; r < 4; ++r)
                    rs[mf][r] += __shfl_xor(rs[mf][r], off, 64);
        if (lr == 0)
#pragma unroll
            for (int mf = 0; mf < 4; ++mf)
#pragma unroll
                for (int r = 0; r < 4; ++r)
                    spart[w][mf * 16 + lg * 4 + r] = rs[mf][r];
    }
    barrier_lds();

    if (tid < LT) {
        float s = Vb[0];
#pragma unroll
        for (int ww = 0; ww < 8; ++ww) s += spart[ww][tid];
        float e = __expf(s);
        el[tid] = e;
        el_arr[(size_t)b * Lsz + l0 + tid] = e;
        float es = e;
#pragma unroll
        for (int off = 1; off < 64; off <<= 1) es += __shfl_xor(es, off, 64);
        if (tid == 0) atomicAdd(&den[b], es);
    }
    barrier_lds();

    {
        const int qr = tid >> 8;
        const int d0 = (tid & 255) * 2;
        float a0 = 0.f, a1 = 0.f;
#pragma unroll 8
        for (int li = 0; li < 32; ++li) {
            int l = qr * 32 + li;
            unsigned int pk = *reinterpret_cast<const unsigned int*>(&A[l][SW(l, d0)]);
            float e = el[l];
            a0 = fmaf(e, bf2f(pk & 0xFFFFu), a0);
            a1 = fmaf(e, bf2f(pk >> 16), a1);
        }
        pc[qr][d0]     = a0;
        pc[qr][d0 + 1] = a1;
    }
    barrier_lds();
    atomicAdd(&ctx_acc[b * Dsz + tid], pc[0][tid] + pc[1][tid]);
}

__global__ __launch_bounds__(256) void k_finalize(const float* __restrict__ el_arr,
                                                  const float* __restrict__ den,
                                                  const float* __restrict__ ctx_acc,
                                                  float* __restrict__ ctx,
                                                  float* __restrict__ wout) {
    int blk = blockIdx.x, tid = threadIdx.x;
    int b = blk >> 2, q = blk & 3;
    float inv = 1.f / den[b];
    size_t base = (size_t)b * Lsz + q * 1024 + tid * 4;
    f4v e4 = *reinterpret_cast<const f4v*>(&el_arr[base]);
    f4v w4 = { e4.x * inv, e4.y * inv, e4.z * inv, e4.w * inv };
    *reinterpret_cast<f4v*>(&wout[base]) = w4;
    if (tid < 128) {
        int d = q * 128 + tid;
        ctx[(size_t)b * Dsz + d] = ctx_acc[b * Dsz + d] * inv;
    }
}

// ===================== ABLATION kernels (write only to dump) =====================
#define KEEP(x) asm volatile("" :: "v"(x))

// S: R11's exact staging pipeline, x6 reps (rotated tiles), no GEMM.
__global__ void __launch_bounds__(512)
__attribute__((amdgpu_waves_per_eu(4, 4))) k_ab_stage(const float* __restrict__ feat,
                                                      float* __restrict__ dump) {
    __shared__ __align__(16) unsigned short A[LT][Dsz];
    const int tid  = threadIdx.x;
    const int b    = blockIdx.x >> 6;
    const int lb0  = blockIdx.x & 63;
    const int srow = tid >> 3;
    const int sfc  = (tid & 7) * 16;
    float keep = 0.f;
#pragma unroll 1
    for (int rep = 0; rep < 6; ++rep) {
        const int lb = (lb0 + rep * 21) & 63;
        const float* fb = feat + ((size_t)b * Lsz + lb * LT + srow) * Dsz + sfc;
        f4v st[2][4];
#pragma unroll
        for (int i = 0; i < 4; ++i) st[0][i] = *reinterpret_cast<const f4v*>(fb + i * 4);
#pragma unroll
        for (int i = 0; i < 4; ++i) st[1][i] = *reinterpret_cast<const f4v*>(fb + 128 + i * 4);
        __builtin_amdgcn_sched_barrier(0);
        {
            u16x8 o0 = { f2bf(st[0][0].x), f2bf(st[0][0].y), f2bf(st[0][0].z), f2bf(st[0][0].w),
                         f2bf(st[0][1].x), f2bf(st[0][1].y), f2bf(st[0][1].z), f2bf(st[0][1].w) };
            u16x8 o1 = { f2bf(st[0][2].x), f2bf(st[0][2].y), f2bf(st[0][2].z), f2bf(st[0][2].w),
                         f2bf(st[0][3].x), f2bf(st[0][3].y), f2bf(st[0][3].z), f2bf(st[0][3].w) };
            *reinterpret_cast<u16x8*>(&A[srow][SW(srow, sfc)])     = o0;
            *reinterpret_cast<u16x8*>(&A[srow][SW(srow, sfc + 8)]) = o1;
        }
        barrier_lds();
#pragma unroll
        for (int c = 0; c < 4; ++c) {
            if (c < 2) {
#pragma unroll
                for (int i = 0; i < 4; ++i)
                    st[c & 1][i] = *reinterpret_cast<const f4v*>(fb + (c + 2) * 128 + i * 4);
            }
            __builtin_amdgcn_sched_barrier(0);
            if (c < 3) {
                const int cc = (c + 1) * 128 + sfc;
                const f4v* s = st[(c + 1) & 1];
                u16x8 o0 = { f2bf(s[0].x), f2bf(s[0].y), f2bf(s[0].z), f2bf(s[0].w),
                             f2bf(s[1].x), f2bf(s[1].y), f2bf(s[1].z), f2bf(s[1].w) };
                u16x8 o1 = { f2bf(s[2].x), f2bf(s[2].y), f2bf(s[2].z), f2bf(s[2].w),
                             f2bf(s[3].x), f2bf(s[3].y), f2bf(s[3].z), f2bf(s[3].w) };
                *reinterpret_cast<u16x8*>(&A[srow][SW(srow, cc)])     = o0;
                *reinterpret_cast<u16x8*>(&A[srow][SW(srow, cc + 8)]) = o1;
                barrier_lds();
            }
        }
        unsigned int pk = *reinterpret_cast<const unsigned int*>(&A[srow][SW(srow, sfc)]);
        keep += bf2f(pk & 0xFFFFu);
        __syncthreads();
    }
    if (tid == 0) dump[blockIdx.x] = keep;
}

// DMA: same bytes via global_load_lds fp32 (LT=32 tile, 64 KB), x6 reps.
__global__ void __launch_bounds__(512)
__attribute__((amdgpu_waves_per_eu(4, 4))) k_ab_dma(const float* __restrict__ feat,
                                                    float* __restrict__ dump) {
    __shared__ __align__(16) float A32[32][512];
    const int tid  = threadIdx.x;
    const int w    = tid >> 6;
    const int lane = tid & 63;
    const int b    = blockIdx.x >> 7;
    const int lb0  = blockIdx.x & 127;
    float keep = 0.f;
#pragma unroll 1
    for (int rep = 0; rep < 6; ++rep) {
        const int lb = (lb0 + rep * 37) & 127;
        const float* fb = feat + ((size_t)b * Lsz + lb * 32) * Dsz;
#if __has_builtin(__builtin_amdgcn_global_load_lds)
#pragma unroll
        for (int i = 0; i < 8; ++i) {
            int lin = w + i * 8;                 // 1KB LDS line index
            int row = lin >> 1;
            int c0  = (lin & 1) * 256 + lane * 4;
            const float* src = fb + (size_t)row * Dsz + c0;
            float* dst = &A32[0][0] + (size_t)lin * 256 + lane * 4;
            __builtin_amdgcn_global_load_lds(
                (const __attribute__((address_space(1))) unsigned int*)src,
                (__attribute__((address_space(3))) unsigned int*)dst, 16, 0, 0);
        }
        asm volatile("s_waitcnt vmcnt(0)" ::: "memory");
        __builtin_amdgcn_s_barrier();
#else
#pragma unroll
        for (int i = 0; i < 8; ++i) {
            int lin = w + i * 8;
            int row = lin >> 1;
            int c0  = (lin & 1) * 256 + lane * 4;
            *reinterpret_cast<f4v*>(&A32[0][0] + (size_t)lin * 256 + lane * 4) =
                *reinterpret_cast<const f4v*>(fb + (size_t)row * Dsz + c0);
        }
        __syncthreads();
#endif
        keep += A32[lane & 31][w * 64 + lane];
        __syncthreads();
    }
    if (tid == 0) dump[2048 + blockIdx.x] = keep;
}

// G: stage once, then x6 full GEMM (B-L2 + LDS-read + MFMA + tanh epilogue).
__global__ void __launch_bounds__(512)
__attribute__((amdgpu_waves_per_eu(4, 4))) k_ab_gemm(const float* __restrict__ feat,
                                                     const unsigned short* __restrict__ W1T,
                                                     float* __restrict__ dump) {
    __shared__ __align__(16) unsigned short A[LT][Dsz];
    __shared__ float hp[Usz], vv[Usz];
    __shared__ float spart[8][LT];
    const int tid  = threadIdx.x;
    const int w    = tid >> 6;
    const int lane = tid & 63;
    const int lr   = lane & 15;
    const int lg   = lane >> 4;
    const int b    = blockIdx.x >> 6;
    const int lb   = blockIdx.x & 63;
    if (tid < Usz) { hp[tid] = tid * 1e-3f; vv[tid] = 0.05f; }
    {   // simple stage once
        const int srow = tid >> 3, sfc = (tid & 7) * 16;
        const float* fb = feat + ((size_t)b * Lsz + lb * LT + srow) * Dsz + sfc;
#pragma unroll
        for (int j = 0; j < 4; ++j) {
            f4v s0 = *reinterpret_cast<const f4v*>(fb + j * 128);
            f4v s1 = *reinterpret_cast<const f4v*>(fb + j * 128 + 4);
            f4v s2 = *reinterpret_cast<const f4v*>(fb + j * 128 + 8);
            f4v s3 = *reinterpret_cast<const f4v*>(fb + j * 128 + 12);
            u16x8 o0 = { f2bf(s0.x), f2bf(s0.y), f2bf(s0.z), f2bf(s0.w),
                         f2bf(s1.x), f2bf(s1.y), f2bf(s1.z), f2bf(s1.w) };
            u16x8 o1 = { f2bf(s2.x), f2bf(s2.y), f2bf(s2.z), f2bf(s2.w),
                         f2bf(s3.x), f2bf(s3.y), f2bf(s3.z), f2bf(s3.w) };
            const int sc = j * 128 + (tid & 7) * 16;
            *reinterpret_cast<u16x8*>(&A[srow][SW(srow, sc)])     = o0;
            *reinterpret_cast<u16x8*>(&A[srow][SW(srow, sc + 8)]) = o1;
        }
    }
    __syncthreads();
    const unsigned short* bp0 = W1T + (size_t)(w * 32 + lr) * Dsz + lg * 8;
    const unsigned short* bp1 = bp0 + 16 * Dsz;
    float keep = 0.f;
#pragma unroll 1
    for (int rep = 0; rep < 6; ++rep) {
        f4v acc[4][2];
#pragma unroll
        for (int mf = 0; mf < 4; ++mf) {
            acc[mf][0] = (f4v){0.f, 0.f, 0.f, 0.f};
            acc[mf][1] = (f4v){0.f, 0.f, 0.f, 0.f};
        }
#pragma unroll
        for (int c = 0; c < 4; ++c) {
            s8v bq[4][2];
#pragma unroll
            for (int k = 0; k < 4; ++k) {
                bq[k][0] = *reinterpret_cast<const s8v*>(bp0 + (c * 4 + k) * 32);
                bq[k][1] = *reinterpret_cast<const s8v*>(bp1 + (c * 4 + k) * 32);
            }
            __builtin_amdgcn_sched_barrier(0);
#pragma unroll
            for (int k = 0; k < 4; ++k) {
                const int kof = (c * 4 + k) * 32 + lg * 8;
#pragma unroll
                for (int mf = 0; mf < 4; ++mf) {
                    const int row = mf * 16 + lr;
                    s8v a = *reinterpret_cast<const s8v*>(&A[row][SW(row, kof)]);
                    acc[mf][0] = __builtin_amdgcn_mfma_f32_16x16x32_bf16(a, bq[k][0], acc[mf][0], 0, 0, 0);
                    acc[mf][1] = __builtin_amdgcn_mfma_f32_16x16x32_bf16(a, bq[k][1], acc[mf][1], 0, 0, 0);
                }
            }
        }
        float rs[4][4];
#pragma unroll
        for (int mf = 0; mf < 4; ++mf)
#pragma unroll
            for (int r = 0; r < 4; ++r) rs[mf][r] = 0.f;
#pragma unroll
        for (int mf = 0; mf < 4; ++mf)
#pragma unroll
            for (int nf = 0; nf < 2; ++nf) {
                int col = w * 32 + nf * 16 + lr;
                float hpv = hp[col], vvv = vv[col];
#pragma unroll
                for (int r = 0; r < 4; ++r) {
                    float x = acc[mf][nf][r] + hpv;
                    float e = __expf(2.f * x);
                    rs[mf][r] = fmaf(1.f - 2.f / (e + 1.f), vvv, rs[mf][r]);
                }
            }
#pragma unroll
        for (int off = 1; off < 16; off <<= 1)
#pragma unroll
            for (int mf = 0; mf < 4; ++mf)
#pragma unroll
                for (int r = 0; r < 4; ++r)
                    rs[mf][r] += __shfl_xor(rs[mf][r], off, 64);
        if (lr == 0)
#pragma unroll
            for (int mf = 0; mf < 4; ++mf)
#pragma unroll
                for (int r = 0; r < 4; ++r)
                    spart[w][mf * 16 + lg * 4 + r] = rs[mf][r];
        barrier_lds();
        keep += spart[w][lane & 63];
        __syncthreads();
    }
    if (tid == 0) dump[4096 + blockIdx.x] = keep;
}

// C: stage once, then x6 ctx accumulation passes.
__global__ void __launch_bounds__(512)
__attribute__((amdgpu_waves_per_eu(4, 4))) k_ab_ctx(const float* __restrict__ feat,
                                                    float* __restrict__ dump) {
    __shared__ __align__(16) unsigned short A[LT][Dsz];
    __shared__ float el[LT];
    __shared__ float pc[2][Dsz];
    const int tid = threadIdx.x;
    const int b   = blockIdx.x >> 6;
    const int lb  = blockIdx.x & 63;
    {
        const int srow = tid >> 3, sfc = (tid & 7) * 16;
        const float* fb = feat + ((size_t)b * Lsz + lb * LT + srow) * Dsz + sfc;
#pragma unroll
        for (int j = 0; j < 4; ++j) {
            f4v s0 = *reinterpret_cast<const f4v*>(fb + j * 128);
            f4v s1 = *reinterpret_cast<const f4v*>(fb + j * 128 + 4);
            f4v s2 = *reinterpret_cast<const f4v*>(fb + j * 128 + 8);
            f4v s3 = *reinterpret_cast<const f4v*>(fb + j * 128 + 12);
            u16x8 o0 = { f2bf(s0.x), f2bf(s0.y), f2bf(s0.z), f2bf(s0.w),
                         f2bf(s1.x), f2bf(s1.y), f2bf(s1.z), f2bf(s1.w) };
            u16x8 o1 = { f2bf(s2.x), f2bf(s2.y), f2bf(s2.z), f2bf(s2.w),
                         f2bf(s3.x), f2bf(s3.y), f2bf(s3.z), f2bf(s3.w) };
            const int sc = j * 128 + sfc;
            *reinterpret_cast<u16x8*>(&A[srow][SW(srow, sc)])     = o0;
            *reinterpret_cast<u16x8*>(&A[srow][SW(srow, sc + 8)]) = o1;
        }
    }
    if (tid < LT) el[tid] = 1.0f + tid * 1e-4f;
    __syncthreads();
    float keep = 0.f;
#pragma unroll 1
    for (int rep = 0; rep < 6; ++rep) {
        const int qr = tid >> 8;
        const int d0 = (tid & 255) * 2;
        float a0 = 0.f, a1 = 0.f;
#pragma unroll 8
        for (int li = 0; li < 32; ++li) {
            int l = qr * 32 + li;
            unsigned int pk = *reinterpret_cast<const unsigned int*>(&A[l][SW(l, d0)]);
            float e = el[l];
            a0 = fmaf(e, bf2f(pk & 0xFFFFu), a0);
            a1 = fmaf(e, bf2f(pk >> 16), a1);
        }
        pc[qr][d0]     = a0;
        pc[qr][d0 + 1] = a1;
        barrier_lds();
        keep += pc[0][tid] + pc[1][tid];
        __syncthreads();
    }
    if (tid == 0) dump[8192 + blockIdx.x] = keep;
}

extern "C" void kernel_launch(void* const* d_in, const int* in_sizes, int n_in,
                              void* d_out, int out_size, void* d_ws, size_t ws_size,
                              hipStream_t stream) {
    const float* feat   = (const float*)d_in[0];
    const float* hidden = (const float*)d_in[1];
    const float* W1     = (const float*)d_in[2];
    const float* W1b    = (const float*)d_in[3];
    const float* W2     = (const float*)d_in[4];
    const float* W2b    = (const float*)d_in[5];
    const float* Vk     = (const float*)d_in[6];
    const float* Vb     = (const float*)d_in[7];

    unsigned short* w1t = (unsigned short*)d_ws;
    float* hp_part = (float*)((char*)d_ws + 256 * 1024);
    float* el_arr  = (float*)((char*)d_ws + 512 * 1024);
    float* den     = (float*)((char*)d_ws + 1536 * 1024);
    float* ctx_acc = (float*)((char*)d_ws + 1536 * 1024 + 256);
    float* dump    = (float*)((char*)d_ws + 2048 * 1024);

    float* ctx  = (float*)d_out;              // [64, 512]
    float* wout = ctx + Bsz * Dsz;            // [64, 4096, 1]

    k_prep<<<352, 256, 0, stream>>>(W1, hidden, W2, w1t, hp_part, den, ctx_acc);
    k_score_ctx<<<Bsz * NLB, 512, 0, stream>>>(feat, w1t, hp_part, W1b, W2b,
                                               Vk, Vb, el_arr, den, ctx_acc);
    k_finalize<<<Bsz * 4, 256, 0, stream>>>(el_arr, den, ctx_acc, ctx, wout);

    // ---- ablation probes (outputs untouched; dump region only) ----
    k_ab_stage<<<4096, 512, 0, stream>>>(feat, dump);
    k_ab_dma<<<8192, 512, 0, stream>>>(feat, dump);
    k_ab_gemm<<<4096, 512, 0, stream>>>(feat, w1t, dump);
    k_ab_ctx<<<4096, 512, 0, stream>>>(feat, dump);
}

// Round 16
// 243.521 us; speedup vs baseline: 8.2260x; 8.2260x over previous
//
#include <hip/hip_runtime.h>

#define Bsz 64
#define Lsz 4096
#define Dsz 512
#define Hsz 512
#define Usz 256
#define LT  64
#define NLB (Lsz / LT)          // 64 L-tiles per batch -> 4096 blocks

typedef __attribute__((ext_vector_type(8))) short s8v;     // bf16x8 MFMA frag
typedef __attribute__((ext_vector_type(4))) float f4v;
typedef __attribute__((ext_vector_type(8))) unsigned short u16x8;

// XOR swizzle on a [64][512]-short row: 16B slot ^= row&7 (bijective, b128-aligned)
#define SW(r, c) (((((c) >> 3) ^ ((r) & 7)) << 3) | ((c) & 7))

__device__ __forceinline__ unsigned short f2bf(float f) {
    unsigned int u = __float_as_uint(f);
    u += 0x7FFFu + ((u >> 16) & 1u);   // RNE
    return (unsigned short)(u >> 16);
}
__device__ __forceinline__ float bf2f(unsigned int lo16) {
    return __uint_as_float(lo16 << 16);
}
__device__ __forceinline__ void barrier_lds() {
    asm volatile("s_waitcnt lgkmcnt(0)" ::: "memory");
    __builtin_amdgcn_s_barrier();
}
// non-temporal f4v load: feat is stream-once -> keep it OUT of L2 so W1T stays resident
__device__ __forceinline__ f4v nt_load4(const float* p) {
    return __builtin_nontemporal_load(reinterpret_cast<const f4v*>(p));
}

// ws layout
//   [0,     256K)      : W1T bf16 [256][512]
//   [256K,  512K)      : hp_part f32 [4][64][256]
//   [512K, 1536K)      : el_arr f32 [64][4096]
//   [1536K, +256B)     : den f32 [64]
//   [1536K+256, +128K) : ctx_acc f32 [64][512]

__global__ __launch_bounds__(256) void k_prep(const float* __restrict__ W1,
                                              const float* __restrict__ hidden,
                                              const float* __restrict__ W2,
                                              unsigned short* __restrict__ W1T,
                                              float* __restrict__ hp_part,
                                              float* __restrict__ den,
                                              float* __restrict__ ctx_acc) {
    int blk = blockIdx.x, tid = threadIdx.x;
    if (blk < 32) {
        __shared__ unsigned short Lt[64][72];
        int kb = blk >> 2, ub = blk & 3;
        {
            int rr = tid >> 2, c16 = (tid & 3) * 16;
            const float* src = W1 + (size_t)(kb * 64 + rr) * Usz + ub * 64 + c16;
            f4v v0 = *reinterpret_cast<const f4v*>(src);
            f4v v1 = *reinterpret_cast<const f4v*>(src + 4);
            f4v v2 = *reinterpret_cast<const f4v*>(src + 8);
            f4v v3 = *reinterpret_cast<const f4v*>(src + 12);
            u16x8 o0 = { f2bf(v0.x), f2bf(v0.y), f2bf(v0.z), f2bf(v0.w),
                         f2bf(v1.x), f2bf(v1.y), f2bf(v1.z), f2bf(v1.w) };
            u16x8 o1 = { f2bf(v2.x), f2bf(v2.y), f2bf(v2.z), f2bf(v2.w),
                         f2bf(v3.x), f2bf(v3.y), f2bf(v3.z), f2bf(v3.w) };
            *reinterpret_cast<u16x8*>(&Lt[rr][c16])     = o0;
            *reinterpret_cast<u16x8*>(&Lt[rr][c16 + 8]) = o1;
        }
        __syncthreads();
        {
            int ur = tid >> 2, k16 = (tid & 3) * 16;
            u16x8 o0, o1;
#pragma unroll
            for (int i = 0; i < 8; ++i) o0[i] = Lt[k16 + i][ur];
#pragma unroll
            for (int i = 0; i < 8; ++i) o1[i] = Lt[k16 + 8 + i][ur];
            unsigned short* dst = W1T + (size_t)(ub * 64 + ur) * Dsz + kb * 64 + k16;
            *reinterpret_cast<u16x8*>(dst)     = o0;
            *reinterpret_cast<u16x8*>(dst + 8) = o1;
        }
    } else if (blk < 288) {
        int idx = blk - 32;
        int kq = idx >> 6, b = idx & 63;
        const float* hrow = hidden + (size_t)b * Hsz + kq * 128;
        const float* w2p  = W2 + (size_t)(kq * 128) * Usz + tid;
        float a0 = 0.f, a1 = 0.f, a2 = 0.f, a3 = 0.f;
#pragma unroll 8
        for (int k = 0; k < 128; k += 4) {
            a0 = fmaf(hrow[k + 0], w2p[(size_t)(k + 0) * Usz], a0);
            a1 = fmaf(hrow[k + 1], w2p[(size_t)(k + 1) * Usz], a1);
            a2 = fmaf(hrow[k + 2], w2p[(size_t)(k + 2) * Usz], a2);
            a3 = fmaf(hrow[k + 3], w2p[(size_t)(k + 3) * Usz], a3);
        }
        hp_part[((size_t)kq * Bsz + b) * Usz + tid] = (a0 + a1) + (a2 + a3);
    } else {
        int b = blk - 288;
        if (tid == 0) den[b] = 0.f;
        ctx_acc[b * Dsz + tid] = 0.f;
        ctx_acc[b * Dsz + 256 + tid] = 0.f;
    }
}

// R11 pipeline + NON-TEMPORAL feature loads (feat bypasses L2 -> W1T stays
// L2-resident -> B-load latency ~200cy, hidden by 4 waves/SIMD interleave).
__global__ void __launch_bounds__(512)
__attribute__((amdgpu_waves_per_eu(4, 4))) k_score_ctx(
    const float* __restrict__ feat, const unsigned short* __restrict__ W1T,
    const float* __restrict__ hp_part, const float* __restrict__ W1b,
    const float* __restrict__ W2b, const float* __restrict__ Vk,
    const float* __restrict__ Vb, float* __restrict__ el_arr,
    float* __restrict__ den, float* __restrict__ ctx_acc)
{
    __shared__ __align__(16) unsigned short A[LT][Dsz];  // 64 KiB, swizzled
    __shared__ float hp[Usz], vv[Usz];
    __shared__ float spart[8][LT];
    __shared__ float el[LT];
    __shared__ float pc[2][Dsz];

    const int tid  = threadIdx.x;
    const int w    = tid >> 6;
    const int lane = tid & 63;
    const int lr   = lane & 15;
    const int lg   = lane >> 4;
    const int b    = blockIdx.x >> 6;
    const int lb   = blockIdx.x & 63;
    const int l0   = lb * LT;

    const int srow = tid >> 3;
    const int sfc  = (tid & 7) * 16;
    const float* fb = feat + ((size_t)b * Lsz + l0 + srow) * Dsz + sfc;

    f4v st[2][4];
#pragma unroll
    for (int i = 0; i < 4; ++i) st[0][i] = nt_load4(fb + i * 4);
#pragma unroll
    for (int i = 0; i < 4; ++i) st[1][i] = nt_load4(fb + 128 + i * 4);
    __builtin_amdgcn_sched_barrier(0);

    if (tid < Usz) {
        const float* hpb = hp_part + (size_t)b * Usz + tid;
        hp[tid] = (hpb[0] + hpb[Bsz * Usz]) + (hpb[2 * Bsz * Usz] + hpb[3 * Bsz * Usz])
                + W1b[tid] + W2b[tid];
        vv[tid] = Vk[tid];
    }
    {
        u16x8 o0 = { f2bf(st[0][0].x), f2bf(st[0][0].y), f2bf(st[0][0].z), f2bf(st[0][0].w),
                     f2bf(st[0][1].x), f2bf(st[0][1].y), f2bf(st[0][1].z), f2bf(st[0][1].w) };
        u16x8 o1 = { f2bf(st[0][2].x), f2bf(st[0][2].y), f2bf(st[0][2].z), f2bf(st[0][2].w),
                     f2bf(st[0][3].x), f2bf(st[0][3].y), f2bf(st[0][3].z), f2bf(st[0][3].w) };
        *reinterpret_cast<u16x8*>(&A[srow][SW(srow, sfc)])     = o0;
        *reinterpret_cast<u16x8*>(&A[srow][SW(srow, sfc + 8)]) = o1;
    }
    barrier_lds();

    const unsigned short* bp0 = W1T + (size_t)(w * 32 + lr) * Dsz + lg * 8;
    const unsigned short* bp1 = bp0 + 16 * Dsz;
    f4v acc[4][2];
#pragma unroll
    for (int mf = 0; mf < 4; ++mf) {
        acc[mf][0] = (f4v){0.f, 0.f, 0.f, 0.f};
        acc[mf][1] = (f4v){0.f, 0.f, 0.f, 0.f};
    }

#pragma unroll
    for (int c = 0; c < 4; ++c) {
        s8v bq[4][2];
#pragma unroll
        for (int k = 0; k < 4; ++k) {
            bq[k][0] = *reinterpret_cast<const s8v*>(bp0 + (c * 4 + k) * 32);
            bq[k][1] = *reinterpret_cast<const s8v*>(bp1 + (c * 4 + k) * 32);
        }
        __builtin_amdgcn_sched_barrier(0);
        if (c < 2) {
#pragma unroll
            for (int i = 0; i < 4; ++i)
                st[c & 1][i] = nt_load4(fb + (c + 2) * 128 + i * 4);
        }
        __builtin_amdgcn_sched_barrier(0);
#pragma unroll
        for (int k = 0; k < 4; ++k) {
            const int kof = (c * 4 + k) * 32 + lg * 8;
#pragma unroll
            for (int mf = 0; mf < 4; ++mf) {
                const int row = mf * 16 + lr;
                s8v a = *reinterpret_cast<const s8v*>(&A[row][SW(row, kof)]);
                acc[mf][0] = __builtin_amdgcn_mfma_f32_16x16x32_bf16(a, bq[k][0], acc[mf][0], 0, 0, 0);
                acc[mf][1] = __builtin_amdgcn_mfma_f32_16x16x32_bf16(a, bq[k][1], acc[mf][1], 0, 0, 0);
            }
        }
        __builtin_amdgcn_sched_barrier(0);
        if (c < 3) {
            const int cc = (c + 1) * 128 + sfc;
            const f4v* s = st[(c + 1) & 1];
            u16x8 o0 = { f2bf(s[0].x), f2bf(s[0].y), f2bf(s[0].z), f2bf(s[0].w),
                         f2bf(s[1].x), f2bf(s[1].y), f2bf(s[1].z), f2bf(s[1].w) };
            u16x8 o1 = { f2bf(s[2].x), f2bf(s[2].y), f2bf(s[2].z), f2bf(s[2].w),
                         f2bf(s[3].x), f2bf(s[3].y), f2bf(s[3].z), f2bf(s[3].w) };
            *reinterpret_cast<u16x8*>(&A[srow][SW(srow, cc)])     = o0;
            *reinterpret_cast<u16x8*>(&A[srow][SW(srow, cc + 8)]) = o1;
            barrier_lds();
        }
    }

    {
        float rs[4][4];
#pragma unroll
        for (int mf = 0; mf < 4; ++mf)
#pragma unroll
            for (int r = 0; r < 4; ++r) rs[mf][r] = 0.f;
#pragma unroll
        for (int mf = 0; mf < 4; ++mf)
#pragma unroll
            for (int nf = 0; nf < 2; ++nf) {
                int col = w * 32 + nf * 16 + lr;
                float hpv = hp[col], vvv = vv[col];
#pragma unroll
                for (int r = 0; r < 4; ++r) {
                    float x = acc[mf][nf][r] + hpv;
                    float e = __expf(2.f * x);
                    rs[mf][r] = fmaf(1.f - 2.f / (e + 1.f), vvv, rs[mf][r]);
                }
            }
#pragma unroll
        for (int off = 1; off < 16; off <<= 1)
#pragma unroll
            for (int mf = 0; mf < 4; ++mf)
#pragma unroll
                for (int r = 0; r < 4; ++r)
                    rs[mf][r] += __shfl_xor(rs[mf][r], off, 64);
        if (lr == 0)
#pragma unroll
            for (int mf = 0; mf < 4; ++mf)
#pragma unroll
                for (int r = 0; r < 4; ++r)
                    spart[w][mf * 16 + lg * 4 + r] = rs[mf][r];
    }
    barrier_lds();

    if (tid < LT) {
        float s = Vb[0];
#pragma unroll
        for (int ww = 0; ww < 8; ++ww) s += spart[ww][tid];
        float e = __expf(s);
        el[tid] = e;
        el_arr[(size_t)b * Lsz + l0 + tid] = e;
        float es = e;
#pragma unroll
        for (int off = 1; off < 64; off <<= 1) es += __shfl_xor(es, off, 64);
        if (tid == 0) atomicAdd(&den[b], es);
    }
    barrier_lds();

    {
        const int qr = tid >> 8;
        const int d0 = (tid & 255) * 2;
        float a0 = 0.f, a1 = 0.f;
#pragma unroll 8
        for (int li = 0; li < 32; ++li) {
            int l = qr * 32 + li;
            unsigned int pk = *reinterpret_cast<const unsigned int*>(&A[l][SW(l, d0)]);
            float e = el[l];
            a0 = fmaf(e, bf2f(pk & 0xFFFFu), a0);
            a1 = fmaf(e, bf2f(pk >> 16), a1);
        }
        pc[qr][d0]     = a0;
        pc[qr][d0 + 1] = a1;
    }
    barrier_lds();
    atomicAdd(&ctx_acc[b * Dsz + tid], pc[0][tid] + pc[1][tid]);
}

__global__ __launch_bounds__(256) void k_finalize(const float* __restrict__ el_arr,
                                                  const float* __restrict__ den,
                                                  const float* __restrict__ ctx_acc,
                                                  float* __restrict__ ctx,
                                                  float* __restrict__ wout) {
    int blk = blockIdx.x, tid = threadIdx.x;
    int b = blk >> 2, q = blk & 3;
    float inv = 1.f / den[b];
    size_t base = (size_t)b * Lsz + q * 1024 + tid * 4;
    f4v e4 = *reinterpret_cast<const f4v*>(&el_arr[base]);
    f4v w4 = { e4.x * inv, e4.y * inv, e4.z * inv, e4.w * inv };
    *reinterpret_cast<f4v*>(&wout[base]) = w4;
    if (tid < 128) {
        int d = q * 128 + tid;
        ctx[(size_t)b * Dsz + d] = ctx_acc[b * Dsz + d] * inv;
    }
}

extern "C" void kernel_launch(void* const* d_in, const int* in_sizes, int n_in,
                              void* d_out, int out_size, void* d_ws, size_t ws_size,
                              hipStream_t stream) {
    const float* feat   = (const float*)d_in[0];
    const float* hidden = (const float*)d_in[1];
    const float* W1     = (const float*)d_in[2];
    const float* W1b    = (const float*)d_in[3];
    const float* W2     = (const float*)d_in[4];
    const float* W2b    = (const float*)d_in[5];
    const float* Vk     = (const float*)d_in[6];
    const float* Vb     = (const float*)d_in[7];

    unsigned short* w1t = (unsigned short*)d_ws;
    float* hp_part = (float*)((char*)d_ws + 256 * 1024);
    float* el_arr  = (float*)((char*)d_ws + 512 * 1024);
    float* den     = (float*)((char*)d_ws + 1536 * 1024);
    float* ctx_acc = (float*)((char*)d_ws + 1536 * 1024 + 256);

    float* ctx  = (float*)d_out;              // [64, 512]
    float* wout = ctx + Bsz * Dsz;            // [64, 4096, 1]

    k_prep<<<352, 256, 0, stream>>>(W1, hidden, W2, w1t, hp_part, den, ctx_acc);
    k_score_ctx<<<Bsz * NLB, 512, 0, stream>>>(feat, w1t, hp_part, W1b, W2b,
                                               Vk, Vb, el_arr, den, ctx_acc);
    k_finalize<<<Bsz * 4, 256, 0, stream>>>(el_arr, den, ctx_acc, ctx, wout);
}

// Round 17
// 201.924 us; speedup vs baseline: 9.9206x; 1.2060x over previous
//
#include <hip/hip_runtime.h>

#define Bsz 64
#define Lsz 4096
#define Dsz 512
#define Hsz 512
#define Usz 256
#define LT  64
#define NLB (Lsz / LT)          // 64 L-tiles per batch -> 4096 blocks

typedef __attribute__((ext_vector_type(8))) short s8v;     // bf16x8 MFMA frag
typedef __attribute__((ext_vector_type(4))) float f4v;
typedef __attribute__((ext_vector_type(8))) unsigned short u16x8;

// XOR swizzle on a [64][512]-short row: 16B slot ^= row&7 (bijective, b128-aligned)
#define SW(r, c) (((((c) >> 3) ^ ((r) & 7)) << 3) | ((c) & 7))

__device__ __forceinline__ unsigned short f2bf(float f) {
    unsigned int u = __float_as_uint(f);
    u += 0x7FFFu + ((u >> 16) & 1u);   // RNE
    return (unsigned short)(u >> 16);
}
__device__ __forceinline__ float bf2f(unsigned int lo16) {
    return __uint_as_float(lo16 << 16);
}
__device__ __forceinline__ void barrier_lds() {
    asm volatile("s_waitcnt lgkmcnt(0)" ::: "memory");
    __builtin_amdgcn_s_barrier();
}

// ws layout
//   [0,     256K)      : W1T bf16 [256][512]
//   [256K,  512K)      : hp_part f32 [4][64][256]
//   [512K, 1536K)      : el_arr f32 [64][4096]
//   [1536K, +256B)     : den f32 [64]
//   [1536K+256, +128K) : ctx_acc f32 [64][512]

__global__ __launch_bounds__(256) void k_prep(const float* __restrict__ W1,
                                              const float* __restrict__ hidden,
                                              const float* __restrict__ W2,
                                              unsigned short* __restrict__ W1T,
                                              float* __restrict__ hp_part,
                                              float* __restrict__ den,
                                              float* __restrict__ ctx_acc) {
    int blk = blockIdx.x, tid = threadIdx.x;
    if (blk < 32) {
        __shared__ unsigned short Lt[64][72];
        int kb = blk >> 2, ub = blk & 3;
        {
            int rr = tid >> 2, c16 = (tid & 3) * 16;
            const float* src = W1 + (size_t)(kb * 64 + rr) * Usz + ub * 64 + c16;
            f4v v0 = *reinterpret_cast<const f4v*>(src);
            f4v v1 = *reinterpret_cast<const f4v*>(src + 4);
            f4v v2 = *reinterpret_cast<const f4v*>(src + 8);
            f4v v3 = *reinterpret_cast<const f4v*>(src + 12);
            u16x8 o0 = { f2bf(v0.x), f2bf(v0.y), f2bf(v0.z), f2bf(v0.w),
                         f2bf(v1.x), f2bf(v1.y), f2bf(v1.z), f2bf(v1.w) };
            u16x8 o1 = { f2bf(v2.x), f2bf(v2.y), f2bf(v2.z), f2bf(v2.w),
                         f2bf(v3.x), f2bf(v3.y), f2bf(v3.z), f2bf(v3.w) };
            *reinterpret_cast<u16x8*>(&Lt[rr][c16])     = o0;
            *reinterpret_cast<u16x8*>(&Lt[rr][c16 + 8]) = o1;
        }
        __syncthreads();
        {
            int ur = tid >> 2, k16 = (tid & 3) * 16;
            u16x8 o0, o1;
#pragma unroll
            for (int i = 0; i < 8; ++i) o0[i] = Lt[k16 + i][ur];
#pragma unroll
            for (int i = 0; i < 8; ++i) o1[i] = Lt[k16 + 8 + i][ur];
            unsigned short* dst = W1T + (size_t)(ub * 64 + ur) * Dsz + kb * 64 + k16;
            *reinterpret_cast<u16x8*>(dst)     = o0;
            *reinterpret_cast<u16x8*>(dst + 8) = o1;
        }
    } else if (blk < 288) {
        int idx = blk - 32;
        int kq = idx >> 6, b = idx & 63;
        const float* hrow = hidden + (size_t)b * Hsz + kq * 128;
        const float* w2p  = W2 + (size_t)(kq * 128) * Usz + tid;
        float a0 = 0.f, a1 = 0.f, a2 = 0.f, a3 = 0.f;
#pragma unroll 8
        for (int k = 0; k < 128; k += 4) {
            a0 = fmaf(hrow[k + 0], w2p[(size_t)(k + 0) * Usz], a0);
            a1 = fmaf(hrow[k + 1], w2p[(size_t)(k + 1) * Usz], a1);
            a2 = fmaf(hrow[k + 2], w2p[(size_t)(k + 2) * Usz], a2);
            a3 = fmaf(hrow[k + 3], w2p[(size_t)(k + 3) * Usz], a3);
        }
        hp_part[((size_t)kq * Bsz + b) * Usz + tid] = (a0 + a1) + (a2 + a3);
    } else {
        int b = blk - 288;
        if (tid == 0) den[b] = 0.f;
        ctx_acc[b * Dsz + tid] = 0.f;
        ctx_acc[b * Dsz + 256 + tid] = 0.f;
    }
}

// R11 pipeline, de-lockstepped: full-tile prologue staging (no barriers inside
// the GEMM), and per-wave ROTATED K-chunk order (cc = (c + w) & 3) so the 4
// waves/SIMD hit their B-load vmcnt stalls at different times and cover each
// other with MFMA/LDS work. K-accumulation is order-independent.
__global__ void __launch_bounds__(512)
__attribute__((amdgpu_waves_per_eu(4, 4))) k_score_ctx(
    const float* __restrict__ feat, const unsigned short* __restrict__ W1T,
    const float* __restrict__ hp_part, const float* __restrict__ W1b,
    const float* __restrict__ W2b, const float* __restrict__ Vk,
    const float* __restrict__ Vb, float* __restrict__ el_arr,
    float* __restrict__ den, float* __restrict__ ctx_acc)
{
    __shared__ __align__(16) unsigned short A[LT][Dsz];  // 64 KiB, swizzled
    __shared__ float hp[Usz], vv[Usz];
    __shared__ float spart[8][LT];
    __shared__ float el[LT];
    __shared__ float pc[2][Dsz];

    const int tid  = threadIdx.x;
    const int w    = tid >> 6;
    const int lane = tid & 63;
    const int lr   = lane & 15;
    const int lg   = lane >> 4;
    const int b    = blockIdx.x >> 6;
    const int lb   = blockIdx.x & 63;
    const int l0   = lb * LT;

    const int srow = tid >> 3;
    const int sfc  = (tid & 7) * 16;
    const float* fb = feat + ((size_t)b * Lsz + l0 + srow) * Dsz + sfc;

    // ---- prologue: stage the FULL 64x512 tile (pipelined ring, <=8 f4v live) ----
    f4v st[2][4];
#pragma unroll
    for (int i = 0; i < 4; ++i) st[0][i] = *reinterpret_cast<const f4v*>(fb + i * 4);
#pragma unroll
    for (int i = 0; i < 4; ++i) st[1][i] = *reinterpret_cast<const f4v*>(fb + 128 + i * 4);
    __builtin_amdgcn_sched_barrier(0);

    if (tid < Usz) {
        const float* hpb = hp_part + (size_t)b * Usz + tid;
        hp[tid] = (hpb[0] + hpb[Bsz * Usz]) + (hpb[2 * Bsz * Usz] + hpb[3 * Bsz * Usz])
                + W1b[tid] + W2b[tid];
        vv[tid] = Vk[tid];
    }

#pragma unroll
    for (int c = 0; c < 4; ++c) {
        // write chunk c (waits only on its own 4 loads; later loads stay in flight)
        {
            const f4v* s = st[c & 1];
            const int cc = c * 128 + sfc;
            u16x8 o0 = { f2bf(s[0].x), f2bf(s[0].y), f2bf(s[0].z), f2bf(s[0].w),
                         f2bf(s[1].x), f2bf(s[1].y), f2bf(s[1].z), f2bf(s[1].w) };
            u16x8 o1 = { f2bf(s[2].x), f2bf(s[2].y), f2bf(s[2].z), f2bf(s[2].w),
                         f2bf(s[3].x), f2bf(s[3].y), f2bf(s[3].z), f2bf(s[3].w) };
            *reinterpret_cast<u16x8*>(&A[srow][SW(srow, cc)])     = o0;
            *reinterpret_cast<u16x8*>(&A[srow][SW(srow, cc + 8)]) = o1;
        }
        // issue chunk c+2 loads into the buffer just freed
        if (c < 2) {
#pragma unroll
            for (int i = 0; i < 4; ++i)
                st[c & 1][i] = *reinterpret_cast<const f4v*>(fb + (c + 2) * 128 + i * 4);
        }
        __builtin_amdgcn_sched_barrier(0);
    }
    barrier_lds();

    // ---- GEMM: barrier-free, per-wave rotated chunk order ----
    const unsigned short* bp0 = W1T + (size_t)(w * 32 + lr) * Dsz + lg * 8;
    const unsigned short* bp1 = bp0 + 16 * Dsz;
    const int wrot = w & 3;
    f4v acc[4][2];
#pragma unroll
    for (int mf = 0; mf < 4; ++mf) {
        acc[mf][0] = (f4v){0.f, 0.f, 0.f, 0.f};
        acc[mf][1] = (f4v){0.f, 0.f, 0.f, 0.f};
    }

#pragma unroll
    for (int c = 0; c < 4; ++c) {
        const int cc = (c + wrot) & 3;          // rotated K-chunk
        s8v bq[4][2];
#pragma unroll
        for (int k = 0; k < 4; ++k) {
            bq[k][0] = *reinterpret_cast<const s8v*>(bp0 + (cc * 4 + k) * 32);
            bq[k][1] = *reinterpret_cast<const s8v*>(bp1 + (cc * 4 + k) * 32);
        }
        __builtin_amdgcn_sched_barrier(0);
#pragma unroll
        for (int k = 0; k < 4; ++k) {
            const int kof = (cc * 4 + k) * 32 + lg * 8;
#pragma unroll
            for (int mf = 0; mf < 4; ++mf) {
                const int row = mf * 16 + lr;
                s8v a = *reinterpret_cast<const s8v*>(&A[row][SW(row, kof)]);
                acc[mf][0] = __builtin_amdgcn_mfma_f32_16x16x32_bf16(a, bq[k][0], acc[mf][0], 0, 0, 0);
                acc[mf][1] = __builtin_amdgcn_mfma_f32_16x16x32_bf16(a, bq[k][1], acc[mf][1], 0, 0, 0);
            }
        }
    }

    // ---- epilogue: per-row sum of tanh(x)*V over this wave's 32 cols ----
    {
        float rs[4][4];
#pragma unroll
        for (int mf = 0; mf < 4; ++mf)
#pragma unroll
            for (int r = 0; r < 4; ++r) rs[mf][r] = 0.f;
#pragma unroll
        for (int mf = 0; mf < 4; ++mf)
#pragma unroll
            for (int nf = 0; nf < 2; ++nf) {
                int col = w * 32 + nf * 16 + lr;
                float hpv = hp[col], vvv = vv[col];
#pragma unroll
                for (int r = 0; r < 4; ++r) {
                    float x = acc[mf][nf][r] + hpv;
                    float e = __expf(2.f * x);
                    rs[mf][r] = fmaf(1.f - 2.f / (e + 1.f), vvv, rs[mf][r]);
                }
            }
#pragma unroll
        for (int off = 1; off < 16; off <<= 1)
#pragma unroll
            for (int mf = 0; mf < 4; ++mf)
#pragma unroll
                for (int r = 0; r < 4; ++r)
                    rs[mf][r] += __shfl_xor(rs[mf][r], off, 64);
        if (lr == 0)
#pragma unroll
            for (int mf = 0; mf < 4; ++mf)
#pragma unroll
                for (int r = 0; r < 4; ++r)
                    spart[w][mf * 16 + lg * 4 + r] = rs[mf][r];
    }
    barrier_lds();

    if (tid < LT) {
        float s = Vb[0];
#pragma unroll
        for (int ww = 0; ww < 8; ++ww) s += spart[ww][tid];
        float e = __expf(s);
        el[tid] = e;
        el_arr[(size_t)b * Lsz + l0 + tid] = e;
        float es = e;
#pragma unroll
        for (int off = 1; off < 64; off <<= 1) es += __shfl_xor(es, off, 64);
        if (tid == 0) atomicAdd(&den[b], es);
    }
    barrier_lds();

    {
        const int qr = tid >> 8;
        const int d0 = (tid & 255) * 2;
        float a0 = 0.f, a1 = 0.f;
#pragma unroll 8
        for (int li = 0; li < 32; ++li) {
            int l = qr * 32 + li;
            unsigned int pk = *reinterpret_cast<const unsigned int*>(&A[l][SW(l, d0)]);
            float e = el[l];
            a0 = fmaf(e, bf2f(pk & 0xFFFFu), a0);
            a1 = fmaf(e, bf2f(pk >> 16), a1);
        }
        pc[qr][d0]     = a0;
        pc[qr][d0 + 1] = a1;
    }
    barrier_lds();
    atomicAdd(&ctx_acc[b * Dsz + tid], pc[0][tid] + pc[1][tid]);
}

__global__ __launch_bounds__(256) void k_finalize(const float* __restrict__ el_arr,
                                                  const float* __restrict__ den,
                                                  const float* __restrict__ ctx_acc,
                                                  float* __restrict__ ctx,
                                                  float* __restrict__ wout) {
    int blk = blockIdx.x, tid = threadIdx.x;
    int b = blk >> 2, q = blk & 3;
    float inv = 1.f / den[b];
    size_t base = (size_t)b * Lsz + q * 1024 + tid * 4;
    f4v e4 = *reinterpret_cast<const f4v*>(&el_arr[base]);
    f4v w4 = { e4.x * inv, e4.y * inv, e4.z * inv, e4.w * inv };
    *reinterpret_cast<f4v*>(&wout[base]) = w4;
    if (tid < 128) {
        int d = q * 128 + tid;
        ctx[(size_t)b * Dsz + d] = ctx_acc[b * Dsz + d] * inv;
    }
}

extern "C" void kernel_launch(void* const* d_in, const int* in_sizes, int n_in,
                              void* d_out, int out_size, void* d_ws, size_t ws_size,
                              hipStream_t stream) {
    const float* feat   = (const float*)d_in[0];
    const float* hidden = (const float*)d_in[1];
    const float* W1     = (const float*)d_in[2];
    const float* W1b    = (const float*)d_in[3];
    const float* W2     = (const float*)d_in[4];
    const float* W2b    = (const float*)d_in[5];
    const float* Vk     = (const float*)d_in[6];
    const float* Vb     = (const float*)d_in[7];

    unsigned short* w1t = (unsigned short*)d_ws;
    float* hp_part = (float*)((char*)d_ws + 256 * 1024);
    float* el_arr  = (float*)((char*)d_ws + 512 * 1024);
    float* den     = (float*)((char*)d_ws + 1536 * 1024);
    float* ctx_acc = (float*)((char*)d_ws + 1536 * 1024 + 256);

    float* ctx  = (float*)d_out;              // [64, 512]
    float* wout = ctx + Bsz * Dsz;            // [64, 4096, 1]

    k_prep<<<352, 256, 0, stream>>>(W1, hidden, W2, w1t, hp_part, den, ctx_acc);
    k_score_ctx<<<Bsz * NLB, 512, 0, stream>>>(feat, w1t, hp_part, W1b, W2b,
                                               Vk, Vb, el_arr, den, ctx_acc);
    k_finalize<<<Bsz * 4, 256, 0, stream>>>(el_arr, den, ctx_acc, ctx, wout);
}

// Round 18
// 163.798 us; speedup vs baseline: 12.2297x; 1.2328x over previous
//
#include <hip/hip_runtime.h>

#define Bsz 64
#define Lsz 4096
#define Dsz 512
#define Hsz 512
#define Usz 256
#define LT  64
#define NLB (Lsz / LT)          // 64 L-tiles per batch -> 4096 blocks

typedef __attribute__((ext_vector_type(8))) short s8v;     // bf16x8 MFMA frag
typedef __attribute__((ext_vector_type(4))) float f4v;
typedef __attribute__((ext_vector_type(8))) unsigned short u16x8;

// XOR swizzle on a [64][512]-short row: 16B slot ^= row&7 (bijective, b128-aligned)
#define SW(r, c) (((((c) >> 3) ^ ((r) & 7)) << 3) | ((c) & 7))

__device__ __forceinline__ unsigned short f2bf(float f) {
    unsigned int u = __float_as_uint(f);
    u += 0x7FFFu + ((u >> 16) & 1u);   // RNE
    return (unsigned short)(u >> 16);
}
__device__ __forceinline__ float bf2f(unsigned int lo16) {
    return __uint_as_float(lo16 << 16);
}
__device__ __forceinline__ void barrier_lds() {
    asm volatile("s_waitcnt lgkmcnt(0)" ::: "memory");
    __builtin_amdgcn_s_barrier();
}

// ws layout
//   [0,     256K)      : W1Tf bf16, FRAGMENT-ORDER: [kb32][colgrp][lg][lr][8]
//                        element (k,u) at ((k>>5)*16 + (u>>4))*512 + (((k>>3)&3)*16 + (u&15))*8 + (k&7)
//   [256K,  512K)      : hp_part f32 [4][64][256]
//   [512K, 1536K)      : el_arr f32 [64][4096]
//   [1536K, +256B)     : den f32 [64]
//   [1536K+256, +128K) : ctx_acc f32 [64][512]

__global__ __launch_bounds__(256) void k_prep(const float* __restrict__ W1,
                                              const float* __restrict__ hidden,
                                              const float* __restrict__ W2,
                                              unsigned short* __restrict__ W1Tf,
                                              float* __restrict__ hp_part,
                                              float* __restrict__ den,
                                              float* __restrict__ ctx_acc) {
    int blk = blockIdx.x, tid = threadIdx.x;
    if (blk < 32) {
        __shared__ unsigned short Lt[64][72];   // [k within 64][u within 64], padded
        int kb = blk >> 2, ub = blk & 3;        // 64-k block, 64-u block
        {
            int rr = tid >> 2, c16 = (tid & 3) * 16;   // k-row, u-chunk
            const float* src = W1 + (size_t)(kb * 64 + rr) * Usz + ub * 64 + c16;
            f4v v0 = *reinterpret_cast<const f4v*>(src);
            f4v v1 = *reinterpret_cast<const f4v*>(src + 4);
            f4v v2 = *reinterpret_cast<const f4v*>(src + 8);
            f4v v3 = *reinterpret_cast<const f4v*>(src + 12);
            u16x8 o0 = { f2bf(v0.x), f2bf(v0.y), f2bf(v0.z), f2bf(v0.w),
                         f2bf(v1.x), f2bf(v1.y), f2bf(v1.z), f2bf(v1.w) };
            u16x8 o1 = { f2bf(v2.x), f2bf(v2.y), f2bf(v2.z), f2bf(v2.w),
                         f2bf(v3.x), f2bf(v3.y), f2bf(v3.z), f2bf(v3.w) };
            *reinterpret_cast<u16x8*>(&Lt[rr][c16])     = o0;
            *reinterpret_cast<u16x8*>(&Lt[rr][c16 + 8]) = o1;
        }
        __syncthreads();
        {
            int ur = tid >> 2, k16 = (tid & 3) * 16;   // u-row, k-chunk (16 k's)
            u16x8 o0, o1;
#pragma unroll
            for (int i = 0; i < 8; ++i) o0[i] = Lt[k16 + i][ur];       // k = kb*64+k16+i
#pragma unroll
            for (int i = 0; i < 8; ++i) o1[i] = Lt[k16 + 8 + i][ur];   // k = kb*64+k16+8+i
            // fragment-order destination
            const int kb32 = kb * 2 + (k16 >> 5);          // 32-k block
            const int lg0  = (k16 >> 3) & 3;               // 0 or 2
            const int cg   = ub * 4 + (ur >> 4);           // 16-col group
            const int lr   = ur & 15;
            unsigned short* d0 = W1Tf + ((size_t)(kb32 * 16 + cg) * 512) + (lg0 * 16 + lr) * 8;
            unsigned short* d1 = W1Tf + ((size_t)(kb32 * 16 + cg) * 512) + ((lg0 + 1) * 16 + lr) * 8;
            *reinterpret_cast<u16x8*>(d0) = o0;
            *reinterpret_cast<u16x8*>(d1) = o1;
        }
    } else if (blk < 288) {
        int idx = blk - 32;
        int kq = idx >> 6, b = idx & 63;
        const float* hrow = hidden + (size_t)b * Hsz + kq * 128;
        const float* w2p  = W2 + (size_t)(kq * 128) * Usz + tid;
        float a0 = 0.f, a1 = 0.f, a2 = 0.f, a3 = 0.f;
#pragma unroll 8
        for (int k = 0; k < 128; k += 4) {
            a0 = fmaf(hrow[k + 0], w2p[(size_t)(k + 0) * Usz], a0);
            a1 = fmaf(hrow[k + 1], w2p[(size_t)(k + 1) * Usz], a1);
            a2 = fmaf(hrow[k + 2], w2p[(size_t)(k + 2) * Usz], a2);
            a3 = fmaf(hrow[k + 3], w2p[(size_t)(k + 3) * Usz], a3);
        }
        hp_part[((size_t)kq * Bsz + b) * Usz + tid] = (a0 + a1) + (a2 + a3);
    } else {
        int b = blk - 288;
        if (tid == 0) den[b] = 0.f;
        ctx_acc[b * Dsz + tid] = 0.f;
        ctx_acc[b * Dsz + 256 + tid] = 0.f;
    }
}

// R11 pipeline (best measured, 191us) with FRAGMENT-ORDER B loads:
// every B-frag load is base + lane*16B -> one contiguous 1KB wave-load
// (16 consecutive 64B segments) instead of 16 segments at 1KB stride.
__global__ void __launch_bounds__(512)
__attribute__((amdgpu_waves_per_eu(4, 4))) k_score_ctx(
    const float* __restrict__ feat, const unsigned short* __restrict__ W1Tf,
    const float* __restrict__ hp_part, const float* __restrict__ W1b,
    const float* __restrict__ W2b, const float* __restrict__ Vk,
    const float* __restrict__ Vb, float* __restrict__ el_arr,
    float* __restrict__ den, float* __restrict__ ctx_acc)
{
    __shared__ __align__(16) unsigned short A[LT][Dsz];  // 64 KiB, swizzled
    __shared__ float hp[Usz], vv[Usz];
    __shared__ float spart[8][LT];
    __shared__ float el[LT];
    __shared__ float pc[2][Dsz];

    const int tid  = threadIdx.x;
    const int w    = tid >> 6;
    const int lane = tid & 63;
    const int lr   = lane & 15;
    const int lg   = lane >> 4;
    const int b    = blockIdx.x >> 6;
    const int lb   = blockIdx.x & 63;
    const int l0   = lb * LT;

    const int srow = tid >> 3;
    const int sfc  = (tid & 7) * 16;
    const float* fb = feat + ((size_t)b * Lsz + l0 + srow) * Dsz + sfc;

    f4v st[2][4];
#pragma unroll
    for (int i = 0; i < 4; ++i) st[0][i] = *reinterpret_cast<const f4v*>(fb + i * 4);
#pragma unroll
    for (int i = 0; i < 4; ++i) st[1][i] = *reinterpret_cast<const f4v*>(fb + 128 + i * 4);
    __builtin_amdgcn_sched_barrier(0);

    if (tid < Usz) {
        const float* hpb = hp_part + (size_t)b * Usz + tid;
        hp[tid] = (hpb[0] + hpb[Bsz * Usz]) + (hpb[2 * Bsz * Usz] + hpb[3 * Bsz * Usz])
                + W1b[tid] + W2b[tid];
        vv[tid] = Vk[tid];
    }
    {
        u16x8 o0 = { f2bf(st[0][0].x), f2bf(st[0][0].y), f2bf(st[0][0].z), f2bf(st[0][0].w),
                     f2bf(st[0][1].x), f2bf(st[0][1].y), f2bf(st[0][1].z), f2bf(st[0][1].w) };
        u16x8 o1 = { f2bf(st[0][2].x), f2bf(st[0][2].y), f2bf(st[0][2].z), f2bf(st[0][2].w),
                     f2bf(st[0][3].x), f2bf(st[0][3].y), f2bf(st[0][3].z), f2bf(st[0][3].w) };
        *reinterpret_cast<u16x8*>(&A[srow][SW(srow, sfc)])     = o0;
        *reinterpret_cast<u16x8*>(&A[srow][SW(srow, sfc + 8)]) = o1;
    }
    barrier_lds();

    // fragment-order B base: frag (kb, cg=w*2+nf) at (kb*16+cg)*512 shorts, + lane*8
    const unsigned short* bpf = W1Tf + (size_t)(w * 2) * 512 + lane * 8;
    f4v acc[4][2];
#pragma unroll
    for (int mf = 0; mf < 4; ++mf) {
        acc[mf][0] = (f4v){0.f, 0.f, 0.f, 0.f};
        acc[mf][1] = (f4v){0.f, 0.f, 0.f, 0.f};
    }

#pragma unroll
    for (int c = 0; c < 4; ++c) {
        s8v bq[4][2];
#pragma unroll
        for (int k = 0; k < 4; ++k) {
            const size_t kbo = (size_t)((c * 4 + k) * 16) * 512;
            bq[k][0] = *reinterpret_cast<const s8v*>(bpf + kbo);
            bq[k][1] = *reinterpret_cast<const s8v*>(bpf + kbo + 512);
        }
        __builtin_amdgcn_sched_barrier(0);
        if (c < 2) {
#pragma unroll
            for (int i = 0; i < 4; ++i)
                st[c & 1][i] = *reinterpret_cast<const f4v*>(fb + (c + 2) * 128 + i * 4);
        }
        __builtin_amdgcn_sched_barrier(0);
#pragma unroll
        for (int k = 0; k < 4; ++k) {
            const int kof = (c * 4 + k) * 32 + lg * 8;
#pragma unroll
            for (int mf = 0; mf < 4; ++mf) {
                const int row = mf * 16 + lr;
                s8v a = *reinterpret_cast<const s8v*>(&A[row][SW(row, kof)]);
                acc[mf][0] = __builtin_amdgcn_mfma_f32_16x16x32_bf16(a, bq[k][0], acc[mf][0], 0, 0, 0);
                acc[mf][1] = __builtin_amdgcn_mfma_f32_16x16x32_bf16(a, bq[k][1], acc[mf][1], 0, 0, 0);
            }
        }
        __builtin_amdgcn_sched_barrier(0);
        if (c < 3) {
            const int cc = (c + 1) * 128 + sfc;
            const f4v* s = st[(c + 1) & 1];
            u16x8 o0 = { f2bf(s[0].x), f2bf(s[0].y), f2bf(s[0].z), f2bf(s[0].w),
                         f2bf(s[1].x), f2bf(s[1].y), f2bf(s[1].z), f2bf(s[1].w) };
            u16x8 o1 = { f2bf(s[2].x), f2bf(s[2].y), f2bf(s[2].z), f2bf(s[2].w),
                         f2bf(s[3].x), f2bf(s[3].y), f2bf(s[3].z), f2bf(s[3].w) };
            *reinterpret_cast<u16x8*>(&A[srow][SW(srow, cc)])     = o0;
            *reinterpret_cast<u16x8*>(&A[srow][SW(srow, cc + 8)]) = o1;
            barrier_lds();
        }
    }

    {
        float rs[4][4];
#pragma unroll
        for (int mf = 0; mf < 4; ++mf)
#pragma unroll
            for (int r = 0; r < 4; ++r) rs[mf][r] = 0.f;
#pragma unroll
        for (int mf = 0; mf < 4; ++mf)
#pragma unroll
            for (int nf = 0; nf < 2; ++nf) {
                int col = w * 32 + nf * 16 + lr;
                float hpv = hp[col], vvv = vv[col];
#pragma unroll
                for (int r = 0; r < 4; ++r) {
                    float x = acc[mf][nf][r] + hpv;
                    float e = __expf(2.f * x);
                    rs[mf][r] = fmaf(1.f - 2.f / (e + 1.f), vvv, rs[mf][r]);
                }
            }
#pragma unroll
        for (int off = 1; off < 16; off <<= 1)
#pragma unroll
            for (int mf = 0; mf < 4; ++mf)
#pragma unroll
                for (int r = 0; r < 4; ++r)
                    rs[mf][r] += __shfl_xor(rs[mf][r], off, 64);
        if (lr == 0)
#pragma unroll
            for (int mf = 0; mf < 4; ++mf)
#pragma unroll
                for (int r = 0; r < 4; ++r)
                    spart[w][mf * 16 + lg * 4 + r] = rs[mf][r];
    }
    barrier_lds();

    if (tid < LT) {
        float s = Vb[0];
#pragma unroll
        for (int ww = 0; ww < 8; ++ww) s += spart[ww][tid];
        float e = __expf(s);
        el[tid] = e;
        el_arr[(size_t)b * Lsz + l0 + tid] = e;
        float es = e;
#pragma unroll
        for (int off = 1; off < 64; off <<= 1) es += __shfl_xor(es, off, 64);
        if (tid == 0) atomicAdd(&den[b], es);
    }
    barrier_lds();

    {
        const int qr = tid >> 8;
        const int d0 = (tid & 255) * 2;
        float a0 = 0.f, a1 = 0.f;
#pragma unroll 8
        for (int li = 0; li < 32; ++li) {
            int l = qr * 32 + li;
            unsigned int pk = *reinterpret_cast<const unsigned int*>(&A[l][SW(l, d0)]);
            float e = el[l];
            a0 = fmaf(e, bf2f(pk & 0xFFFFu), a0);
            a1 = fmaf(e, bf2f(pk >> 16), a1);
        }
        pc[qr][d0]     = a0;
        pc[qr][d0 + 1] = a1;
    }
    barrier_lds();
    atomicAdd(&ctx_acc[b * Dsz + tid], pc[0][tid] + pc[1][tid]);
}

__global__ __launch_bounds__(256) void k_finalize(const float* __restrict__ el_arr,
                                                  const float* __restrict__ den,
                                                  const float* __restrict__ ctx_acc,
                                                  float* __restrict__ ctx,
                                                  float* __restrict__ wout) {
    int blk = blockIdx.x, tid = threadIdx.x;
    int b = blk >> 2, q = blk & 3;
    float inv = 1.f / den[b];
    size_t base = (size_t)b * Lsz + q * 1024 + tid * 4;
    f4v e4 = *reinterpret_cast<const f4v*>(&el_arr[base]);
    f4v w4 = { e4.x * inv, e4.y * inv, e4.z * inv, e4.w * inv };
    *reinterpret_cast<f4v*>(&wout[base]) = w4;
    if (tid < 128) {
        int d = q * 128 + tid;
        ctx[(size_t)b * Dsz + d] = ctx_acc[b * Dsz + d] * inv;
    }
}

extern "C" void kernel_launch(void* const* d_in, const int* in_sizes, int n_in,
                              void* d_out, int out_size, void* d_ws, size_t ws_size,
                              hipStream_t stream) {
    const float* feat   = (const float*)d_in[0];
    const float* hidden = (const float*)d_in[1];
    const float* W1     = (const float*)d_in[2];
    const float* W1b    = (const float*)d_in[3];
    const float* W2     = (const float*)d_in[4];
    const float* W2b    = (const float*)d_in[5];
    const float* Vk     = (const float*)d_in[6];
    const float* Vb     = (const float*)d_in[7];

    unsigned short* w1tf = (unsigned short*)d_ws;
    float* hp_part = (float*)((char*)d_ws + 256 * 1024);
    float* el_arr  = (float*)((char*)d_ws + 512 * 1024);
    float* den     = (float*)((char*)d_ws + 1536 * 1024);
    float* ctx_acc = (float*)((char*)d_ws + 1536 * 1024 + 256);

    float* ctx  = (float*)d_out;              // [64, 512]
    float* wout = ctx + Bsz * Dsz;            // [64, 4096, 1]

    k_prep<<<352, 256, 0, stream>>>(W1, hidden, W2, w1tf, hp_part, den, ctx_acc);
    k_score_ctx<<<Bsz * NLB, 512, 0, stream>>>(feat, w1tf, hp_part, W1b, W2b,
                                               Vk, Vb, el_arr, den, ctx_acc);
    k_finalize<<<Bsz * 4, 256, 0, stream>>>(el_arr, den, ctx_acc, ctx, wout);
}